// Round 5
// baseline (214.675 us; speedup 1.0000x reference)
//
#include <hip/hip_runtime.h>

#define MNODES 384
#define RTHRESH 0.05f
#define NBLOCKS 256

// ---------------------------------------------------------------------------
// Single persistent cooperative-launched kernel, hand-rolled grid barrier.
// Grid = 256 blocks x 384 threads (6 waves/block = 6 nodes/block, exactly
// 1 block/CU -> co-residency guaranteed by hipLaunchCooperativeKernel).
// Wave <-> node fixed: node = blk*6 + wave. 384/6=64 blocks/batch (no
// block straddles a batch). State in wave-uniform registers; neighbor
// lists in per-wave LDS (built once); phi ping-pongs in d_ws.
// Phases:  [adj + phi0->A] B [agg0(A)+g0 + phi1->B] B [agg1(B)+g1 + phi2->A]
//          B [agg2(A)+g2 -> out]
// Barrier: release fence + relaxed atomicAdd arrive + RELAXED spin (no
// cache-inv per poll — this is what makes it ~100x cheaper than ROCm's
// cg grid.sync) + single acquire fence on exit. Fence-fence sync through
// the counter RMW chain gives cross-XCD visibility of phi.
// Workspace: barrier cnt[3] @ 0 (zeroed via hipMemsetAsync, 16 B),
//            phiA @ 256, phiB @ 256+786432.
// ---------------------------------------------------------------------------

__device__ __forceinline__ void gridbar(unsigned* __restrict__ c) {
    __syncthreads();
    if (threadIdx.x == 0) {
        __builtin_amdgcn_fence(__ATOMIC_RELEASE, "agent");          // flush phi writes
        __hip_atomic_fetch_add(c, 1u, __ATOMIC_RELAXED, __HIP_MEMORY_SCOPE_AGENT);
        while (__hip_atomic_load(c, __ATOMIC_RELAXED, __HIP_MEMORY_SCOPE_AGENT) != NBLOCKS)
            __builtin_amdgcn_s_sleep(1);
        __builtin_amdgcn_fence(__ATOMIC_ACQUIRE, "agent");          // one invalidate
    }
    __syncthreads();
}

// phi[node][128] = relu(W3^T relu(W2^T relu(W1[3:6]^T s + b1) + b2) + b3)
// Per-wave LDS H1/H2; wave-internal DS ordering -> no barriers needed
// (validated bit-exact rounds 3-4).
__device__ __forceinline__ void phi_stage(
    const float* __restrict__ fW1, const float* __restrict__ fb1,
    const float* __restrict__ fW2, const float* __restrict__ fb2,
    const float* __restrict__ fW3, const float* __restrict__ fb3,
    float s0, float s1, float s2, int lane,
    float* __restrict__ H1, float* __restrict__ H2,
    float* __restrict__ phidst)
{
    // Layer 1 (effective 3->64; rel slot of the edge input is exactly zero,
    // so rows 0..2 of fW1 are provably unused)
    float v = fb1[lane];
    v = fmaf(s0, fW1[3 * 64 + lane], v);
    v = fmaf(s1, fW1[4 * 64 + lane], v);
    v = fmaf(s2, fW1[5 * 64 + lane], v);
    H1[lane] = fmaxf(v, 0.0f);
    // Layer 2: 64 -> 128
    float a0 = fb2[lane], a1 = fb2[lane + 64];
#pragma unroll 16
    for (int c = 0; c < 64; ++c) {
        const float h = H1[c];
        a0 = fmaf(h, fW2[c * 128 + lane], a0);
        a1 = fmaf(h, fW2[c * 128 + lane + 64], a1);
    }
    H2[lane] = fmaxf(a0, 0.0f);
    H2[lane + 64] = fmaxf(a1, 0.0f);
    // Layer 3: 128 -> 128, final relu
    float c0 = fb3[lane], c1 = fb3[lane + 64];
#pragma unroll 16
    for (int c = 0; c < 128; ++c) {
        const float h = H2[c];
        c0 = fmaf(h, fW3[c * 128 + lane], c0);
        c1 = fmaf(h, fW3[c * 128 + lane + 64], c1);
    }
    phidst[lane] = fmaxf(c0, 0.0f);
    phidst[lane + 64] = fmaxf(c1, 0.0f);
}

__global__ __launch_bounds__(384) void fused_gnn(
    const float* __restrict__ x,
    const float* __restrict__ fW1, const float* __restrict__ fb1,
    const float* __restrict__ fW2, const float* __restrict__ fb2,
    const float* __restrict__ fW3, const float* __restrict__ fb3,
    const float* __restrict__ gW1, const float* __restrict__ gb1,
    const float* __restrict__ gW2, const float* __restrict__ gb2,
    const float* __restrict__ gW3, const float* __restrict__ gb3,
    unsigned* __restrict__ bar,
    float* __restrict__ phiA, float* __restrict__ phiB,
    float* __restrict__ out)
{
    __shared__ float xs[MNODES * 3];
    __shared__ float work[6][224];            // aggL[0:128)|h1[128:192)|h2[192:224); phi: H1[0:64)|H2[64:192)
    __shared__ unsigned short nlist[6][384];  // per-wave neighbor list (persists)

    const int tid = threadIdx.x;
    const int wv = tid >> 6, lane = tid & 63;
    const int blk = blockIdx.x;
    const int node = blk * 6 + wv;            // [0,1536)
    const int n = blk >> 6;                   // batch (64 blocks per batch)
    const int i = node - n * MNODES;
    const int nbase = n * MNODES;

    // ---- Phase 0: stage coords, adjacency, phi(t=0) -> phiA ----
    for (int idx = tid; idx < MNODES * 3; idx += 384)
        xs[idx] = x[n * MNODES * 3 + idx];
    __syncthreads();

    float s0 = xs[i * 3 + 0], s1 = xs[i * 3 + 1], s2 = xs[i * 3 + 2];  // wave-uniform

    int nc = 0;
    {
        unsigned short* ml = &nlist[wv][0];
#pragma unroll
        for (int rep = 0; rep < 6; ++rep) {
            const int j = rep * 64 + lane;
            float dx = xs[j * 3 + 0] - s0;
            float dy = xs[j * 3 + 1] - s1;
            float dz = xs[j * 3 + 2] - s2;
            // match numpy rounding exactly (no fp-contract): (dx*dx + dy*dy) + dz*dz
            float d2 = __fadd_rn(__fadd_rn(__fmul_rn(dx, dx), __fmul_rn(dy, dy)),
                                 __fmul_rn(dz, dz));
            const bool a = d2 < RTHRESH;
            const unsigned long long m = __ballot(a);
            if (a) ml[nc + __popcll(m & ((1ull << lane) - 1ull))] = (unsigned short)j;
            nc += (int)__popcll(m);
        }
    }

    float* const H1 = &work[wv][0];
    float* const H2 = &work[wv][64];
    phi_stage(fW1, fb1, fW2, fb2, fW3, fb3, s0, s1, s2, lane, H1, H2,
              phiA + (size_t)node * 128);
    gridbar(bar + 0);

    // ---- Phases 1..3 ----
    for (int t = 0; t < 3; ++t) {
        const float* pb = ((t & 1) ? phiB : phiA) + (size_t)nbase * 128;
        // agg: max over neighbors, float2 per lane (channels 2*lane, 2*lane+1).
        // phi >= 0 and non-neighbors contribute 0 in the reference, so init 0
        // exact. 8-wide with index clamping (duplicates harmless under max);
        // nc >= 1 always (self-edge: d2 = 0 < R).
        float mx[8], my[8];
#pragma unroll
        for (int k = 0; k < 8; ++k) { mx[k] = 0.0f; my[k] = 0.0f; }
        {
            const unsigned short* ml = &nlist[wv][0];
            const int last = nc - 1;
            for (int jj = 0; jj < nc; jj += 8) {
                const float2* r[8];
#pragma unroll
                for (int k = 0; k < 8; ++k) {
                    const int jc = jj + k;
                    const int j = ml[jc < last ? jc : last];
                    r[k] = (const float2*)(pb + (size_t)j * 128);
                }
#pragma unroll
                for (int k = 0; k < 8; ++k) {
                    const float2 v = r[k][lane];
                    mx[k] = fmaxf(mx[k], v.x);
                    my[k] = fmaxf(my[k], v.y);
                }
            }
        }
        float* const aggL = &work[wv][0];
        float* const h1L  = &work[wv][128];
        float* const h2L  = &work[wv][192];
        ((float2*)aggL)[lane] = make_float2(
            fmaxf(fmaxf(fmaxf(mx[0], mx[1]), fmaxf(mx[2], mx[3])),
                  fmaxf(fmaxf(mx[4], mx[5]), fmaxf(mx[6], mx[7]))),
            fmaxf(fmaxf(fmaxf(my[0], my[1]), fmaxf(my[2], my[3])),
                  fmaxf(fmaxf(my[4], my[5]), fmaxf(my[6], my[7]))));

        const float* gW1t = gW1 + t * 8192;
        const float* gW2t = gW2 + t * 2048;
        const float* gW3t = gW3 + t * 96;

        // g1: 128 -> 64
        float h = gb1[t * 64 + lane];
#pragma unroll 16
        for (int c = 0; c < 128; ++c) h = fmaf(aggL[c], gW1t[c * 64 + lane], h);
        h1L[lane] = fmaxf(h, 0.0f);
        // g2: 64 -> 32
        if (lane < 32) {
            float v2 = gb2[t * 32 + lane];
#pragma unroll 16
            for (int k = 0; k < 64; ++k) v2 = fmaf(h1L[k], gW2t[k * 32 + lane], v2);
            h2L[lane] = fmaxf(v2, 0.0f);
        }
        // g3: 32 -> 3, final relu, residual
        float ns = 0.0f;
        if (lane < 3) {
            float v3 = gb3[t * 3 + lane];
#pragma unroll
            for (int q = 0; q < 32; ++q) v3 = fmaf(h2L[q], gW3t[q * 3 + lane], v3);
            ns = fmaxf(v3, 0.0f) + ((lane == 0) ? s0 : (lane == 1) ? s1 : s2);
        }
        s0 = __shfl(ns, 0); s1 = __shfl(ns, 1); s2 = __shfl(ns, 2);

        if (t == 2) {
            if (lane < 3) out[node * 3 + lane] = ns;
        } else {
            const int tn = t + 1;
            float* pdst = (tn & 1) ? phiB : phiA;
            phi_stage(fW1 + tn * 384, fb1 + tn * 64,
                      fW2 + tn * 8192, fb2 + tn * 128,
                      fW3 + tn * 16384, fb3 + tn * 128,
                      s0, s1, s2, lane, H1, H2, pdst + (size_t)node * 128);
            gridbar(bar + 1 + t);
        }
    }
}

extern "C" void kernel_launch(void* const* d_in, const int* in_sizes, int n_in,
                              void* d_out, int out_size, void* d_ws, size_t ws_size,
                              hipStream_t stream) {
    const float* x   = (const float*)d_in[0];
    // d_in[1..6] = hW1..hb3 : provably unused (delta MLP receives exact zeros)
    const float* fW1 = (const float*)d_in[7];
    const float* fb1 = (const float*)d_in[8];
    const float* fW2 = (const float*)d_in[9];
    const float* fb2 = (const float*)d_in[10];
    const float* fW3 = (const float*)d_in[11];
    const float* fb3 = (const float*)d_in[12];
    const float* gW1 = (const float*)d_in[13];
    const float* gb1 = (const float*)d_in[14];
    const float* gW2 = (const float*)d_in[15];
    const float* gb2 = (const float*)d_in[16];
    const float* gW3 = (const float*)d_in[17];
    const float* gb3 = (const float*)d_in[18];

    char* ws = (char*)d_ws;
    unsigned* bar = (unsigned*)ws;                 // 3 counters, zeroed below
    float* phiA   = (float*)(ws + 256);
    float* phiB   = (float*)(ws + 256 + 786432);
    float* outp   = (float*)d_out;

    hipMemsetAsync(bar, 0, 16, stream);            // graph-legal memset node

    void* args[] = {
        (void*)&x,
        (void*)&fW1, (void*)&fb1, (void*)&fW2, (void*)&fb2, (void*)&fW3, (void*)&fb3,
        (void*)&gW1, (void*)&gb1, (void*)&gW2, (void*)&gb2, (void*)&gW3, (void*)&gb3,
        (void*)&bar, (void*)&phiA, (void*)&phiB, (void*)&outp
    };
    hipLaunchCooperativeKernel((const void*)fused_gnn, dim3(NBLOCKS), dim3(384),
                               args, 0, stream);
}

// Round 6
// 186.880 us; speedup vs baseline: 1.1487x; 1.1487x over previous
//
#include <hip/hip_runtime.h>

#define MNODES 384
#define RTHRESH 0.05f
#define NBLOCKS 256

typedef unsigned long long ull;

// ---------------------------------------------------------------------------
// Single cooperative kernel, NO grid barriers: fine-grained per-node dataflow.
// Grid = 256 blocks x 384 threads (6 waves = 6 nodes per block, 1 block/CU,
// co-residency guaranteed by hipLaunchCooperativeKernel). node = blk*6 + wv;
// 64 blocks per batch (blocks never straddle batches).
//
// Transport: phi rows are written with agent-scope RELAXED atomic 64-bit
// stores (write-through to the coherence point; local L2 stays clean), then
// s_waitcnt(0), then a relaxed per-node epoch-flag store. Consumers poll only
// their ~25 neighbors' flags, then gather rows with agent-scope relaxed
// atomic 64-bit loads. No fences anywhere -> no L2 invalidates -> weights
// stay cached across phases; no contended RMW barrier arrives.
//
// Epochs: phi(t) published with flag value t+1 (1,2,3; flags zeroed by a
// hipMemsetAsync each replay). Phase t polls flag >= t+1. phi ping-pongs
// A (t even) / B (t odd). WAR safety across the 2-phase reuse distance:
// j overwrites row_j in A at phase t+2 only after consuming phi_i(t+1) for
// all i in N(j) (adjacency is symmetric); i published phi_i(t+1) only after
// an s_waitcnt(0) that drained i's phase-t gather loads of row_j. So every
// reader's loads completed before the overwrite. Proven bit-exact chain.
//
// Workspace: flags @ 0 (1536 x 128 B = 196608), phiA @ 196608 (786432),
//            phiB @ 983040 (786432).
// ---------------------------------------------------------------------------

__device__ __forceinline__ ull pack2(float a, float b) {
    return (ull)__float_as_uint(a) | ((ull)__float_as_uint(b) << 32);
}
__device__ __forceinline__ float lo2(ull u) { return __uint_as_float((unsigned)u); }
__device__ __forceinline__ float hi2(ull u) { return __uint_as_float((unsigned)(u >> 32)); }

// phi[node][128]; paired-neuron mapping: lane computes neurons 2*lane and
// 2*lane+1 (per-neuron arithmetic order unchanged -> bit-exact; weights and
// phi move as dwordx2). Per-wave LDS H1/H2, wave-internal DS ordering (no
// barriers; validated bit-exact rounds 3-5). Row stored via agent-relaxed
// atomic 64-bit stores.
__device__ __forceinline__ void phi_stage(
    const float* __restrict__ fW1, const float* __restrict__ fb1,
    const float* __restrict__ fW2, const float* __restrict__ fb2,
    const float* __restrict__ fW3, const float* __restrict__ fb3,
    float s0, float s1, float s2, int lane,
    float* __restrict__ H1, float* __restrict__ H2,
    ull* __restrict__ phirow /* node's row as ull[64] */)
{
    // Layer 1 (effective 3->64; rel slot of the edge input is exactly zero,
    // so rows 0..2 of fW1 are provably unused). One neuron per lane.
    float v = fb1[lane];
    v = fmaf(s0, fW1[3 * 64 + lane], v);
    v = fmaf(s1, fW1[4 * 64 + lane], v);
    v = fmaf(s2, fW1[5 * 64 + lane], v);
    H1[lane] = fmaxf(v, 0.0f);
    // Layer 2: 64 -> 128, neurons 2*lane, 2*lane+1
    const float2 b2 = *(const float2*)(fb2 + 2 * lane);
    float a0 = b2.x, a1 = b2.y;
#pragma unroll 16
    for (int c = 0; c < 64; ++c) {
        const float h = H1[c];
        const float2 w = *(const float2*)(fW2 + c * 128 + 2 * lane);
        a0 = fmaf(h, w.x, a0);
        a1 = fmaf(h, w.y, a1);
    }
    ((float2*)H2)[lane] = make_float2(fmaxf(a0, 0.0f), fmaxf(a1, 0.0f));
    // Layer 3: 128 -> 128, final relu
    const float2 b3 = *(const float2*)(fb3 + 2 * lane);
    float c0 = b3.x, c1 = b3.y;
#pragma unroll 16
    for (int c = 0; c < 128; ++c) {
        const float h = H2[c];
        const float2 w = *(const float2*)(fW3 + c * 128 + 2 * lane);
        c0 = fmaf(h, w.x, c0);
        c1 = fmaf(h, w.y, c1);
    }
    __hip_atomic_store(phirow + lane, pack2(fmaxf(c0, 0.0f), fmaxf(c1, 0.0f)),
                       __ATOMIC_RELAXED, __HIP_MEMORY_SCOPE_AGENT);
}

// Publish: drain ALL this wave's outstanding memory ops (vmcnt is per-wave,
// so lane 0's s_waitcnt covers every lane's phi stores AND prior gather
// loads), then relaxed flag store. Signal fences pin compiler ordering.
__device__ __forceinline__ void publish(unsigned* __restrict__ flags, int node,
                                        unsigned ep, int lane) {
    __atomic_signal_fence(__ATOMIC_SEQ_CST);
    __builtin_amdgcn_s_waitcnt(0);
    __atomic_signal_fence(__ATOMIC_SEQ_CST);
    if (lane == 0)
        __hip_atomic_store(flags + (size_t)node * 32, ep,
                           __ATOMIC_RELAXED, __HIP_MEMORY_SCOPE_AGENT);
}

// Poll neighbor flags (rounds of 64; nc can exceed 64 in principle).
__device__ __forceinline__ void pollnb(const unsigned* __restrict__ flags, int nbase,
                                       const unsigned short* __restrict__ ml, int nc,
                                       unsigned ep, int lane) {
    for (int base = 0; base < nc; base += 64) {
        const int idx = base + lane;
        const bool need = idx < nc;
        const unsigned* fp = flags + (size_t)(nbase + (need ? ml[idx] : 0)) * 32;
        while (true) {
            const unsigned f = __hip_atomic_load(fp, __ATOMIC_RELAXED,
                                                 __HIP_MEMORY_SCOPE_AGENT);
            if (__ballot(need && f < ep) == 0ull) break;
            __builtin_amdgcn_s_sleep(1);
        }
    }
}

__global__ __launch_bounds__(384) void fused_gnn(
    const float* __restrict__ x,
    const float* __restrict__ fW1, const float* __restrict__ fb1,
    const float* __restrict__ fW2, const float* __restrict__ fb2,
    const float* __restrict__ fW3, const float* __restrict__ fb3,
    const float* __restrict__ gW1, const float* __restrict__ gb1,
    const float* __restrict__ gW2, const float* __restrict__ gb2,
    const float* __restrict__ gW3, const float* __restrict__ gb3,
    unsigned* __restrict__ flags,
    ull* __restrict__ phiA, ull* __restrict__ phiB,
    float* __restrict__ out)
{
    __shared__ float xs[MNODES * 3];
    __shared__ float work[6][224];            // aggL[0:128)|h1[128:192)|h2[192:224); phi: H1[0:64)|H2[64:192)
    __shared__ unsigned short nlist[6][384];  // per-wave neighbor list (persists)

    const int tid = threadIdx.x;
    const int wv = tid >> 6, lane = tid & 63;
    const int blk = blockIdx.x;
    const int node = blk * 6 + wv;            // [0,1536)
    const int n = blk >> 6;                   // batch (64 blocks per batch)
    const int i = node - n * MNODES;
    const int nbase = n * MNODES;

    // ---- Phase 0: stage coords, adjacency, phi(t=0) -> phiA, flag=1 ----
    for (int idx = tid; idx < MNODES * 3; idx += 384)
        xs[idx] = x[n * MNODES * 3 + idx];
    __syncthreads();

    float s0 = xs[i * 3 + 0], s1 = xs[i * 3 + 1], s2 = xs[i * 3 + 2];  // wave-uniform

    int nc = 0;
    {
        unsigned short* ml = &nlist[wv][0];
#pragma unroll
        for (int rep = 0; rep < 6; ++rep) {
            const int j = rep * 64 + lane;
            float dx = xs[j * 3 + 0] - s0;
            float dy = xs[j * 3 + 1] - s1;
            float dz = xs[j * 3 + 2] - s2;
            // match numpy rounding exactly (no fp-contract): (dx*dx + dy*dy) + dz*dz
            float d2 = __fadd_rn(__fadd_rn(__fmul_rn(dx, dx), __fmul_rn(dy, dy)),
                                 __fmul_rn(dz, dz));
            const bool a = d2 < RTHRESH;
            const unsigned long long m = __ballot(a);
            if (a) ml[nc + __popcll(m & ((1ull << lane) - 1ull))] = (unsigned short)j;
            nc += (int)__popcll(m);
        }
    }

    float* const H1 = &work[wv][0];
    float* const H2 = &work[wv][64];
    phi_stage(fW1, fb1, fW2, fb2, fW3, fb3, s0, s1, s2, lane, H1, H2,
              phiA + (size_t)node * 64);
    publish(flags, node, 1u, lane);

    // ---- Phases 1..3: poll neighbors, agg+g, then phi(t+1) or out ----
    for (int t = 0; t < 3; ++t) {
        const unsigned short* ml = &nlist[wv][0];
        pollnb(flags, nbase, ml, nc, (unsigned)(t + 1), lane);

        const ull* pb = ((t & 1) ? phiB : phiA) + (size_t)nbase * 64;
        // agg: max over neighbors, channels (2*lane, 2*lane+1) per lane.
        // phi >= 0 and non-neighbors contribute 0 in the reference, so init 0
        // exact. 8-wide with index clamping (duplicates harmless under max);
        // nc >= 1 always (self-edge: d2 = 0 < R). Agent-relaxed atomic loads
        // bypass the (possibly stale) local L2.
        float mx[8], my[8];
#pragma unroll
        for (int k = 0; k < 8; ++k) { mx[k] = 0.0f; my[k] = 0.0f; }
        {
            const int last = nc - 1;
            for (int jj = 0; jj < nc; jj += 8) {
                const ull* r[8];
#pragma unroll
                for (int k = 0; k < 8; ++k) {
                    const int jc = jj + k;
                    const int j = ml[jc < last ? jc : last];
                    r[k] = pb + (size_t)j * 64;
                }
#pragma unroll
                for (int k = 0; k < 8; ++k) {
                    const ull u = __hip_atomic_load(r[k] + lane, __ATOMIC_RELAXED,
                                                    __HIP_MEMORY_SCOPE_AGENT);
                    mx[k] = fmaxf(mx[k], lo2(u));
                    my[k] = fmaxf(my[k], hi2(u));
                }
            }
        }
        float* const aggL = &work[wv][0];
        float* const h1L  = &work[wv][128];
        float* const h2L  = &work[wv][192];
        ((float2*)aggL)[lane] = make_float2(
            fmaxf(fmaxf(fmaxf(mx[0], mx[1]), fmaxf(mx[2], mx[3])),
                  fmaxf(fmaxf(mx[4], mx[5]), fmaxf(mx[6], mx[7]))),
            fmaxf(fmaxf(fmaxf(my[0], my[1]), fmaxf(my[2], my[3])),
                  fmaxf(fmaxf(my[4], my[5]), fmaxf(my[6], my[7]))));

        const float* gW1t = gW1 + t * 8192;
        const float* gW2t = gW2 + t * 2048;
        const float* gW3t = gW3 + t * 96;

        // g1: 128 -> 64
        float h = gb1[t * 64 + lane];
#pragma unroll 16
        for (int c = 0; c < 128; ++c) h = fmaf(aggL[c], gW1t[c * 64 + lane], h);
        h1L[lane] = fmaxf(h, 0.0f);
        // g2: 64 -> 32
        if (lane < 32) {
            float v2 = gb2[t * 32 + lane];
#pragma unroll 16
            for (int k = 0; k < 64; ++k) v2 = fmaf(h1L[k], gW2t[k * 32 + lane], v2);
            h2L[lane] = fmaxf(v2, 0.0f);
        }
        // g3: 32 -> 3, final relu, residual
        float ns = 0.0f;
        if (lane < 3) {
            float v3 = gb3[t * 3 + lane];
#pragma unroll
            for (int q = 0; q < 32; ++q) v3 = fmaf(h2L[q], gW3t[q * 3 + lane], v3);
            ns = fmaxf(v3, 0.0f) + ((lane == 0) ? s0 : (lane == 1) ? s1 : s2);
        }
        s0 = __shfl(ns, 0); s1 = __shfl(ns, 1); s2 = __shfl(ns, 2);

        if (t == 2) {
            if (lane < 3) out[node * 3 + lane] = ns;
        } else {
            const int tn = t + 1;
            ull* pdst = (tn & 1) ? phiB : phiA;
            phi_stage(fW1 + tn * 384, fb1 + tn * 64,
                      fW2 + tn * 8192, fb2 + tn * 128,
                      fW3 + tn * 16384, fb3 + tn * 128,
                      s0, s1, s2, lane, H1, H2, pdst + (size_t)node * 64);
            publish(flags, node, (unsigned)(tn + 1), lane);
        }
    }
}

extern "C" void kernel_launch(void* const* d_in, const int* in_sizes, int n_in,
                              void* d_out, int out_size, void* d_ws, size_t ws_size,
                              hipStream_t stream) {
    const float* x   = (const float*)d_in[0];
    // d_in[1..6] = hW1..hb3 : provably unused (delta MLP receives exact zeros)
    const float* fW1 = (const float*)d_in[7];
    const float* fb1 = (const float*)d_in[8];
    const float* fW2 = (const float*)d_in[9];
    const float* fb2 = (const float*)d_in[10];
    const float* fW3 = (const float*)d_in[11];
    const float* fb3 = (const float*)d_in[12];
    const float* gW1 = (const float*)d_in[13];
    const float* gb1 = (const float*)d_in[14];
    const float* gW2 = (const float*)d_in[15];
    const float* gb2 = (const float*)d_in[16];
    const float* gW3 = (const float*)d_in[17];
    const float* gb3 = (const float*)d_in[18];

    char* ws = (char*)d_ws;
    unsigned* flags = (unsigned*)ws;               // 1536 flags, 128 B apart
    ull* phiA       = (ull*)(ws + 196608);
    ull* phiB       = (ull*)(ws + 983040);
    float* outp     = (float*)d_out;

    hipMemsetAsync(flags, 0, 196608, stream);      // graph-legal memset node

    void* args[] = {
        (void*)&x,
        (void*)&fW1, (void*)&fb1, (void*)&fW2, (void*)&fb2, (void*)&fW3, (void*)&fb3,
        (void*)&gW1, (void*)&gb1, (void*)&gW2, (void*)&gb2, (void*)&gW3, (void*)&gb3,
        (void*)&flags, (void*)&phiA, (void*)&phiB, (void*)&outp
    };
    hipLaunchCooperativeKernel((const void*)fused_gnn, dim3(NBLOCKS), dim3(384),
                               args, 0, stream);
}

// Round 7
// 165.737 us; speedup vs baseline: 1.2953x; 1.1276x over previous
//
#include <hip/hip_runtime.h>

#define MNODES 384
#define RTHRESH 0.05f
#define NBLOCKS 256

typedef unsigned long long ull;

// ---------------------------------------------------------------------------
// Single cooperative kernel, fine-grained per-node dataflow, NO memset node.
// Grid = 256 blocks x 384 threads (6 waves = 6 nodes/block, 1 block/CU).
// node = blk*6 + wv; 64 blocks/batch (blocks never straddle batches).
//
// Transport: phi(t) rows go to a DISTINCT buffer per epoch (phi0/phi1/phi2 —
// no WAR reuse). Writers: agent-scope relaxed atomic 64-bit stores (write-
// through to the memory-side coherence point), s_waitcnt(0), then a relaxed
// per-node token store (token = t+1). Readers: poll neighbor tokens with
// EXACT-match atomic loads (poison 0xAAAAAAAA != any token -> no memset
// needed), then gather rows with ORDINARY CACHED loads: each row address is
// first touched only after its token is visible, and per-epoch buffers are
// never rewritten, so no cache can hold a stale copy (dispatch-boundary
// invalidation guarantees clean caches at kernel start).
// Exact-match safety: adjacency is symmetric, so a writer can only advance
// past token k after all its readers published k (each reader's publish
// follows its successful poll) -> a token is never overwritten before every
// poller has observed it.
//
// fW2/fW3 (98 KB/phase, the dominant stream: otherwise 6 waves x 98 KB per
// CU per phase from L2) are staged into LDS once per block per phase.
// Deadlock-free: tokens for epoch 1 publish unconditionally; body-t polls
// depend only on epoch-t+1 tokens, which all blocks publish before any
// body-t+1 sync, by induction.
//
// Workspace: phi0 @ 0, phi1 @ 786432, phi2 @ 1572864 (each 786432 B),
//            flags @ 2359296 (1536 x 128 B).
// ---------------------------------------------------------------------------

__device__ __forceinline__ ull pack2(float a, float b) {
    return (ull)__float_as_uint(a) | ((ull)__float_as_uint(b) << 32);
}

// Stage fW2(t) [0:8192) and fW3(t) [8192:24576) floats into LDS.
__device__ __forceinline__ void stage_w(const float* __restrict__ fW2t,
                                        const float* __restrict__ fW3t,
                                        float* __restrict__ wds, int tid) {
    float4* d = (float4*)wds;
    const float4* s2 = (const float4*)fW2t;   // 2048 float4
    const float4* s3 = (const float4*)fW3t;   // 4096 float4
#pragma unroll
    for (int k = 0; k < 16; ++k) {            // 16*384 = 6144 float4
        const int idx = tid + k * 384;
        d[idx] = (idx < 2048) ? s2[idx] : s3[idx - 2048];
    }
}

// phi: L1 3->64 (one neuron/lane, fW1 rel-rows 0..2 provably unused),
// L2 64->128 and L3 128->128 with neurons (2*lane, 2*lane+1), weights from
// LDS (float2, 2-way bank aliasing = free). Per-wave H1/H2 in LDS, wave-
// internal DS ordering (no barriers; bit-exact rounds 3-6). Row published
// via agent-relaxed atomic 64-bit stores.
__device__ __forceinline__ void phi_stage(
    const float* __restrict__ fW1, const float* __restrict__ fb1,
    const float* __restrict__ fb2, const float* __restrict__ fb3,
    const float* __restrict__ wds,
    float s0, float s1, float s2, int lane,
    float* __restrict__ H1, float* __restrict__ H2,
    ull* __restrict__ phirow)
{
    float v = fb1[lane];
    v = fmaf(s0, fW1[3 * 64 + lane], v);
    v = fmaf(s1, fW1[4 * 64 + lane], v);
    v = fmaf(s2, fW1[5 * 64 + lane], v);
    H1[lane] = fmaxf(v, 0.0f);
    const float2 b2 = *(const float2*)(fb2 + 2 * lane);
    float a0 = b2.x, a1 = b2.y;
#pragma unroll 16
    for (int c = 0; c < 64; ++c) {
        const float h = H1[c];
        const float2 w = ((const float2*)(wds + c * 128))[lane];
        a0 = fmaf(h, w.x, a0);
        a1 = fmaf(h, w.y, a1);
    }
    ((float2*)H2)[lane] = make_float2(fmaxf(a0, 0.0f), fmaxf(a1, 0.0f));
    const float2 b3 = *(const float2*)(fb3 + 2 * lane);
    float c0 = b3.x, c1 = b3.y;
#pragma unroll 16
    for (int c = 0; c < 128; ++c) {
        const float h = H2[c];
        const float2 w = ((const float2*)(wds + 8192 + c * 128))[lane];
        c0 = fmaf(h, w.x, c0);
        c1 = fmaf(h, w.y, c1);
    }
    __hip_atomic_store(phirow + lane, pack2(fmaxf(c0, 0.0f), fmaxf(c1, 0.0f)),
                       __ATOMIC_RELAXED, __HIP_MEMORY_SCOPE_AGENT);
}

// Drain this wave's phi stores (vmcnt is per-wave: covers all 64 lanes),
// then token store.
__device__ __forceinline__ void publish(unsigned* __restrict__ flags, int node,
                                        unsigned tok, int lane) {
    asm volatile("" ::: "memory");
    __builtin_amdgcn_s_waitcnt(0);
    if (lane == 0)
        __hip_atomic_store(flags + (size_t)node * 32, tok,
                           __ATOMIC_RELAXED, __HIP_MEMORY_SCOPE_AGENT);
    asm volatile("" ::: "memory");
}

// Poll neighbor tokens for EXACT match (rounds of 64).
__device__ __forceinline__ void pollnb(const unsigned* __restrict__ flags, int nbase,
                                       const unsigned short* __restrict__ ml, int nc,
                                       unsigned tok, int lane) {
    for (int base = 0; base < nc; base += 64) {
        const int idx = base + lane;
        const bool need = idx < nc;
        const unsigned* fp = flags + (size_t)(nbase + (need ? ml[idx] : 0)) * 32;
        while (true) {
            const unsigned f = __hip_atomic_load(fp, __ATOMIC_RELAXED,
                                                 __HIP_MEMORY_SCOPE_AGENT);
            if (__ballot(need && f != tok) == 0ull) break;
            __builtin_amdgcn_s_sleep(1);
        }
    }
    asm volatile("" ::: "memory");   // no hoisting gather loads above the poll
}

__global__ __launch_bounds__(384) void fused_gnn(
    const float* __restrict__ x,
    const float* __restrict__ fW1, const float* __restrict__ fb1,
    const float* __restrict__ fW2, const float* __restrict__ fb2,
    const float* __restrict__ fW3, const float* __restrict__ fb3,
    const float* __restrict__ gW1, const float* __restrict__ gb1,
    const float* __restrict__ gW2, const float* __restrict__ gb2,
    const float* __restrict__ gW3, const float* __restrict__ gb3,
    unsigned* __restrict__ flags,
    ull* __restrict__ phi0, ull* __restrict__ phi1, ull* __restrict__ phi2,
    float* __restrict__ out)
{
    __shared__ float xs[MNODES * 3];
    __shared__ float work[6][224];            // phi: H1[0:64)|H2[64:192); agg: aggL[0:128)|h1[128:192)|h2[192:224)
    __shared__ unsigned short nlist[6][384];
    __shared__ float wds[24576];              // staged fW2(t) | fW3(t)

    const int tid = threadIdx.x;
    const int wv = tid >> 6, lane = tid & 63;
    const int blk = blockIdx.x;
    const int node = blk * 6 + wv;            // [0,1536)
    const int n = blk >> 6;                   // batch
    const int i = node - n * MNODES;
    const int nbase = n * MNODES;

    // ---- Phase 0: coords + W(0) staging, adjacency, phi0, token 1 ----
    for (int idx = tid; idx < MNODES * 3; idx += 384)
        xs[idx] = x[n * MNODES * 3 + idx];
    stage_w(fW2, fW3, wds, tid);
    __syncthreads();

    float s0 = xs[i * 3 + 0], s1 = xs[i * 3 + 1], s2 = xs[i * 3 + 2];  // wave-uniform

    int nc = 0;
    {
        unsigned short* ml = &nlist[wv][0];
#pragma unroll
        for (int rep = 0; rep < 6; ++rep) {
            const int j = rep * 64 + lane;
            float dx = xs[j * 3 + 0] - s0;
            float dy = xs[j * 3 + 1] - s1;
            float dz = xs[j * 3 + 2] - s2;
            // match numpy rounding exactly (no fp-contract): (dx*dx + dy*dy) + dz*dz
            float d2 = __fadd_rn(__fadd_rn(__fmul_rn(dx, dx), __fmul_rn(dy, dy)),
                                 __fmul_rn(dz, dz));
            const bool a = d2 < RTHRESH;
            const unsigned long long m = __ballot(a);
            if (a) ml[nc + __popcll(m & ((1ull << lane) - 1ull))] = (unsigned short)j;
            nc += (int)__popcll(m);
        }
    }

    float* const H1 = &work[wv][0];
    float* const H2 = &work[wv][64];
    phi_stage(fW1, fb1, fb2, fb3, wds, s0, s1, s2, lane, H1, H2,
              phi0 + (size_t)node * 64);
    publish(flags, node, 1u, lane);

    // ---- Phases t = 0..2 ----
    for (int t = 0; t < 3; ++t) {
        const unsigned short* ml = &nlist[wv][0];
        pollnb(flags, nbase, ml, nc, (unsigned)(t + 1), lane);

        // gather: ORDINARY cached loads (fresh-line argument in header).
        const ull* pbuf = (t == 0) ? phi0 : (t == 1) ? phi1 : phi2;
        const float2* pb = (const float2*)(pbuf + (size_t)nbase * 64);
        float mx[8], my[8];
#pragma unroll
        for (int k = 0; k < 8; ++k) { mx[k] = 0.0f; my[k] = 0.0f; }
        {
            const int last = nc - 1;
            for (int jj = 0; jj < nc; jj += 8) {
                const float2* r[8];
#pragma unroll
                for (int k = 0; k < 8; ++k) {
                    const int jc = jj + k;
                    const int j = ml[jc < last ? jc : last];   // clamp: dup harmless under max
                    r[k] = pb + (size_t)j * 64;
                }
#pragma unroll
                for (int k = 0; k < 8; ++k) {
                    const float2 v = r[k][lane];
                    mx[k] = fmaxf(mx[k], v.x);
                    my[k] = fmaxf(my[k], v.y);
                }
            }
        }
        float* const aggL = &work[wv][0];
        float* const h1L  = &work[wv][128];
        float* const h2L  = &work[wv][192];
        ((float2*)aggL)[lane] = make_float2(
            fmaxf(fmaxf(fmaxf(mx[0], mx[1]), fmaxf(mx[2], mx[3])),
                  fmaxf(fmaxf(mx[4], mx[5]), fmaxf(mx[6], mx[7]))),
            fmaxf(fmaxf(fmaxf(my[0], my[1]), fmaxf(my[2], my[3])),
                  fmaxf(fmaxf(my[4], my[5]), fmaxf(my[6], my[7]))));

        const float* gW1t = gW1 + t * 8192;
        const float* gW2t = gW2 + t * 2048;
        const float* gW3t = gW3 + t * 96;

        float h = gb1[t * 64 + lane];
#pragma unroll 16
        for (int c = 0; c < 128; ++c) h = fmaf(aggL[c], gW1t[c * 64 + lane], h);
        h1L[lane] = fmaxf(h, 0.0f);
        if (lane < 32) {
            float v2 = gb2[t * 32 + lane];
#pragma unroll 16
            for (int k = 0; k < 64; ++k) v2 = fmaf(h1L[k], gW2t[k * 32 + lane], v2);
            h2L[lane] = fmaxf(v2, 0.0f);
        }
        float ns = 0.0f;
        if (lane < 3) {
            float v3 = gb3[t * 3 + lane];
#pragma unroll
            for (int q = 0; q < 32; ++q) v3 = fmaf(h2L[q], gW3t[q * 3 + lane], v3);
            ns = fmaxf(v3, 0.0f) + ((lane == 0) ? s0 : (lane == 1) ? s1 : s2);
        }
        s0 = __shfl(ns, 0); s1 = __shfl(ns, 1); s2 = __shfl(ns, 2);

        if (t == 2) {
            if (lane < 3) out[node * 3 + lane] = ns;
        } else {
            const int tn = t + 1;
            // All waves of the block are past phi(t)'s wds reads (phi(t)
            // precedes body-t per wave); sync, restage, sync, compute.
            __syncthreads();
            stage_w(fW2 + tn * 8192, fW3 + tn * 16384, wds, tid);
            __syncthreads();
            ull* pdst = (tn == 1) ? phi1 : phi2;
            phi_stage(fW1 + tn * 384, fb1 + tn * 64,
                      fb2 + tn * 128, fb3 + tn * 128, wds,
                      s0, s1, s2, lane, H1, H2, pdst + (size_t)node * 64);
            publish(flags, node, (unsigned)(tn + 1), lane);
        }
    }
}

extern "C" void kernel_launch(void* const* d_in, const int* in_sizes, int n_in,
                              void* d_out, int out_size, void* d_ws, size_t ws_size,
                              hipStream_t stream) {
    const float* x   = (const float*)d_in[0];
    // d_in[1..6] = hW1..hb3 : provably unused (delta MLP receives exact zeros)
    const float* fW1 = (const float*)d_in[7];
    const float* fb1 = (const float*)d_in[8];
    const float* fW2 = (const float*)d_in[9];
    const float* fb2 = (const float*)d_in[10];
    const float* fW3 = (const float*)d_in[11];
    const float* fb3 = (const float*)d_in[12];
    const float* gW1 = (const float*)d_in[13];
    const float* gb1 = (const float*)d_in[14];
    const float* gW2 = (const float*)d_in[15];
    const float* gb2 = (const float*)d_in[16];
    const float* gW3 = (const float*)d_in[17];
    const float* gb3 = (const float*)d_in[18];

    char* ws = (char*)d_ws;
    ull* phi0       = (ull*)(ws + 0);
    ull* phi1       = (ull*)(ws + 786432);
    ull* phi2       = (ull*)(ws + 1572864);
    unsigned* flags = (unsigned*)(ws + 2359296);   // poison-safe: exact-match tokens
    float* outp     = (float*)d_out;

    void* args[] = {
        (void*)&x,
        (void*)&fW1, (void*)&fb1, (void*)&fW2, (void*)&fb2, (void*)&fW3, (void*)&fb3,
        (void*)&gW1, (void*)&gb1, (void*)&gW2, (void*)&gb2, (void*)&gW3, (void*)&gb3,
        (void*)&flags, (void*)&phi0, (void*)&phi1, (void*)&phi2, (void*)&outp
    };
    hipLaunchCooperativeKernel((const void*)fused_gnn, dim3(NBLOCKS), dim3(384),
                               args, 0, stream);
}

// Round 8
// 134.934 us; speedup vs baseline: 1.5910x; 1.2283x over previous
//
#include <hip/hip_runtime.h>

#define MNODES 384
#define RTHRESH 0.05f

// ---------------------------------------------------------------------------
// 4 plain launches (dispatch boundaries carry cross-block phi visibility for
// free — measured far cheaper than any in-kernel sync on this chip):
//   K0: adj + phi(t=0) -> phiA
//   K1: agg0+g0 (x -> stateA)      + phi(t=1) -> phiB
//   K2: agg1+g1 (stateA -> stateB) + phi(t=2) -> phiA
//   K3: agg2+g2 (stateB -> d_out)
//
// Geometry: 768 blocks x 64 threads (1 wave = 2 nodes). No __syncthreads
// anywhere (wave-internal LDS ordering suffices; bit-exact since R3).
// 2 nodes/wave halves the dominant cost (per-wave fW2/fW3 L2 stream:
// 96 KB/wave for 2 nodes instead of 1) at 75% SIMD coverage.
// Mapping: batch = blk & 3 (XCD swizzle: each batch's phi rows are produced
// and consumed on the same 2 XCDs -> L2 gather locality), pair = blk >> 2,
// nodes = batch*384 + 2*pair + {0,1}.
//
// Workspace layout (bytes):
//   lists  @ 0        : 1536*384 u16  (1179648)
//   cnt    @ 1179648  : 1536 int      (6144)
//   phiA   @ 1185792  : 1536*128 f32  (786432)
//   phiB   @ 1972224  : 1536*128 f32  (786432)
//   stateA @ 2758656  : 1536*3 f32    (18432)
//   stateB @ 2777088  : 1536*3 f32    (18432)
// ---------------------------------------------------------------------------

// phi for the wave's 2 nodes; weights streamed once as float2 (neurons
// 2*lane, 2*lane+1), shared by both nodes. Per-neuron accumulation is the
// exact fmaf-ascending chain that has been bit-exact since R1.
__device__ __forceinline__ void phi2_stage(
    const float* __restrict__ fW1, const float* __restrict__ fb1,
    const float* __restrict__ fW2, const float* __restrict__ fb2,
    const float* __restrict__ fW3, const float* __restrict__ fb3,
    float sa0, float sa1, float sa2,   // node A state (wave-uniform)
    float sb0, float sb1, float sb2,   // node B state
    int lane,
    float (*H1)[64], float (*H2)[128],
    float* __restrict__ rowA, float* __restrict__ rowB)
{
    // Layer 1 (effective 3->64): rel slot of the edge input is exactly zero,
    // so rows 0..2 of fW1 are provably unused. Weight cols loaded once.
    const float w3 = fW1[3 * 64 + lane];
    const float w4 = fW1[4 * 64 + lane];
    const float w5 = fW1[5 * 64 + lane];
    const float bb = fb1[lane];
    float va = fmaf(sa2, w5, fmaf(sa1, w4, fmaf(sa0, w3, bb)));
    float vb = fmaf(sb2, w5, fmaf(sb1, w4, fmaf(sb0, w3, bb)));
    H1[0][lane] = fmaxf(va, 0.0f);
    H1[1][lane] = fmaxf(vb, 0.0f);
    // Layer 2: 64 -> 128
    const float2 b2 = ((const float2*)fb2)[lane];
    float a00 = b2.x, a01 = b2.y, a10 = b2.x, a11 = b2.y;
#pragma unroll 16
    for (int c = 0; c < 64; ++c) {
        const float2 w = ((const float2*)(fW2 + c * 128))[lane];
        const float h0 = H1[0][c], h1 = H1[1][c];
        a00 = fmaf(h0, w.x, a00); a01 = fmaf(h0, w.y, a01);
        a10 = fmaf(h1, w.x, a10); a11 = fmaf(h1, w.y, a11);
    }
    ((float2*)H2[0])[lane] = make_float2(fmaxf(a00, 0.0f), fmaxf(a01, 0.0f));
    ((float2*)H2[1])[lane] = make_float2(fmaxf(a10, 0.0f), fmaxf(a11, 0.0f));
    // Layer 3: 128 -> 128, final relu
    const float2 b3 = ((const float2*)fb3)[lane];
    float c00 = b3.x, c01 = b3.y, c10 = b3.x, c11 = b3.y;
#pragma unroll 16
    for (int c = 0; c < 128; ++c) {
        const float2 w = ((const float2*)(fW3 + c * 128))[lane];
        const float h0 = H2[0][c], h1 = H2[1][c];
        c00 = fmaf(h0, w.x, c00); c01 = fmaf(h0, w.y, c01);
        c10 = fmaf(h1, w.x, c10); c11 = fmaf(h1, w.y, c11);
    }
    ((float2*)rowA)[lane] = make_float2(fmaxf(c00, 0.0f), fmaxf(c01, 0.0f));
    ((float2*)rowB)[lane] = make_float2(fmaxf(c10, 0.0f), fmaxf(c11, 0.0f));
}

// K0: adjacency (ballot-compacted u16 neighbor lists) + phi(t=0).
__global__ __launch_bounds__(64) void adj_phi0_kernel(
    const float* __restrict__ x,
    const float* __restrict__ fW1, const float* __restrict__ fb1,
    const float* __restrict__ fW2, const float* __restrict__ fb2,
    const float* __restrict__ fW3, const float* __restrict__ fb3,
    int* __restrict__ cnt, unsigned short* __restrict__ lists,
    float* __restrict__ phiA)
{
    __shared__ float xs[MNODES * 3];
    __shared__ float H1[2][64];
    __shared__ float H2[2][128];
    const int lane = threadIdx.x;
    const int blk = blockIdx.x;
    const int batch = blk & 3;                 // XCD swizzle
    const int i0 = (blk >> 2) * 2;             // local node pair base
    const int g0 = batch * MNODES + i0;        // global node

    // stage batch coords (288 float4); wave-internal LDS ordering, no barrier
    {
        const float4* src = (const float4*)(x + batch * MNODES * 3);
        float4* dst = (float4*)xs;
#pragma unroll
        for (int k = 0; k < 5; ++k) {
            const int idx = lane + k * 64;
            if (idx < 288) dst[idx] = src[idx];
        }
    }

    const float sa0 = xs[i0 * 3 + 0], sa1 = xs[i0 * 3 + 1], sa2 = xs[i0 * 3 + 2];
    const float sb0 = xs[i0 * 3 + 3], sb1 = xs[i0 * 3 + 4], sb2 = xs[i0 * 3 + 5];

#pragma unroll
    for (int r = 0; r < 2; ++r) {
        const float q0 = r ? sb0 : sa0, q1 = r ? sb1 : sa1, q2 = r ? sb2 : sa2;
        unsigned short* ml = lists + (size_t)(g0 + r) * MNODES;
        int nc = 0;
#pragma unroll
        for (int rep = 0; rep < 6; ++rep) {
            const int j = rep * 64 + lane;
            float dx = xs[j * 3 + 0] - q0;
            float dy = xs[j * 3 + 1] - q1;
            float dz = xs[j * 3 + 2] - q2;
            // match numpy rounding exactly (no fp-contract): (dx*dx+dy*dy)+dz*dz
            float d2 = __fadd_rn(__fadd_rn(__fmul_rn(dx, dx), __fmul_rn(dy, dy)),
                                 __fmul_rn(dz, dz));
            const bool a = d2 < RTHRESH;
            const unsigned long long m = __ballot(a);
            if (a) ml[nc + __popcll(m & ((1ull << lane) - 1ull))] = (unsigned short)j;
            nc += (int)__popcll(m);
        }
        if (lane == 0) cnt[g0 + r] = nc;
    }

    phi2_stage(fW1, fb1, fW2, fb2, fW3, fb3,
               sa0, sa1, sa2, sb0, sb1, sb2, lane, H1, H2,
               phiA + (size_t)g0 * 128, phiA + (size_t)(g0 + 1) * 128);
}

// K1..K3: agg(t)+g(t) for the wave's 2 nodes (+ phi(t+1) when do_phi).
__global__ __launch_bounds__(64) void step_kernel(
    const float* __restrict__ phisrc, float* __restrict__ phidst,
    const int* __restrict__ cnt, const unsigned short* __restrict__ lists,
    const float* __restrict__ statesrc, float* __restrict__ statedst,
    const float* __restrict__ gW1, const float* __restrict__ gb1,
    const float* __restrict__ gW2, const float* __restrict__ gb2,
    const float* __restrict__ gW3, const float* __restrict__ gb3,
    const float* __restrict__ fW1n, const float* __restrict__ fb1n,
    const float* __restrict__ fW2n, const float* __restrict__ fb2n,
    const float* __restrict__ fW3n, const float* __restrict__ fb3n,
    int do_phi)
{
    __shared__ float aggL[2][128];
    __shared__ float h1L[2][64];
    __shared__ float h2L[2][32];
    __shared__ float H1[2][64];
    __shared__ float H2[2][128];
    const int lane = threadIdx.x;
    const int blk = blockIdx.x;
    const int batch = blk & 3;                 // XCD swizzle (matches K0)
    const int g0 = batch * MNODES + (blk >> 2) * 2;

    const int nc0 = cnt[g0], nc1 = cnt[g0 + 1];
    const unsigned short* ml0 = lists + (size_t)g0 * MNODES;
    const unsigned short* ml1 = ml0 + MNODES;
    const float2* pb = (const float2*)(phisrc + (size_t)batch * MNODES * 128);

    // agg: max over neighbors for both nodes, 8-deep each (16 outstanding
    // 512B loads). Index clamp: duplicate last neighbor, harmless under max;
    // phi >= 0 and non-neighbors contribute 0 in the reference, so init 0 is
    // exact; nc >= 1 always (self-edge: d2 = 0 < R).
    float mx0[8], my0[8], mx1[8], my1[8];
#pragma unroll
    for (int k = 0; k < 8; ++k) { mx0[k] = my0[k] = mx1[k] = my1[k] = 0.0f; }
    {
        const int last0 = nc0 - 1, last1 = nc1 - 1;
        const int ncm = nc0 > nc1 ? nc0 : nc1;
        for (int jj = 0; jj < ncm; jj += 8) {
            const float2 *r0[8], *r1[8];
#pragma unroll
            for (int k = 0; k < 8; ++k) {
                const int a = jj + k;
                const int j0 = ml0[a < last0 ? a : last0];
                const int j1 = ml1[a < last1 ? a : last1];
                r0[k] = pb + (size_t)j0 * 64;
                r1[k] = pb + (size_t)j1 * 64;
            }
#pragma unroll
            for (int k = 0; k < 8; ++k) {
                const float2 v0 = r0[k][lane], v1 = r1[k][lane];
                mx0[k] = fmaxf(mx0[k], v0.x); my0[k] = fmaxf(my0[k], v0.y);
                mx1[k] = fmaxf(mx1[k], v1.x); my1[k] = fmaxf(my1[k], v1.y);
            }
        }
    }
    ((float2*)aggL[0])[lane] = make_float2(
        fmaxf(fmaxf(fmaxf(mx0[0], mx0[1]), fmaxf(mx0[2], mx0[3])),
              fmaxf(fmaxf(mx0[4], mx0[5]), fmaxf(mx0[6], mx0[7]))),
        fmaxf(fmaxf(fmaxf(my0[0], my0[1]), fmaxf(my0[2], my0[3])),
              fmaxf(fmaxf(my0[4], my0[5]), fmaxf(my0[6], my0[7]))));
    ((float2*)aggL[1])[lane] = make_float2(
        fmaxf(fmaxf(fmaxf(mx1[0], mx1[1]), fmaxf(mx1[2], mx1[3])),
              fmaxf(fmaxf(mx1[4], mx1[5]), fmaxf(mx1[6], mx1[7]))),
        fmaxf(fmaxf(fmaxf(my1[0], my1[1]), fmaxf(my1[2], my1[3])),
              fmaxf(fmaxf(my1[4], my1[5]), fmaxf(my1[6], my1[7]))));

    // g1: 128 -> 64 (weights loaded once, used for both nodes)
    float hA = gb1[lane], hB = hA;
#pragma unroll 16
    for (int c = 0; c < 128; ++c) {
        const float w = gW1[c * 64 + lane];
        hA = fmaf(aggL[0][c], w, hA);
        hB = fmaf(aggL[1][c], w, hB);
    }
    h1L[0][lane] = fmaxf(hA, 0.0f);
    h1L[1][lane] = fmaxf(hB, 0.0f);
    // g2: 64 -> 32
    if (lane < 32) {
        float vA = gb2[lane], vB = vA;
#pragma unroll 16
        for (int k = 0; k < 64; ++k) {
            const float w = gW2[k * 32 + lane];
            vA = fmaf(h1L[0][k], w, vA);
            vB = fmaf(h1L[1][k], w, vB);
        }
        h2L[0][lane] = fmaxf(vA, 0.0f);
        h2L[1][lane] = fmaxf(vB, 0.0f);
    }
    // g3: 32 -> 3, final relu, residual
    float nsA = 0.0f, nsB = 0.0f;
    if (lane < 3) {
        float oA = gb3[lane], oB = oA;
#pragma unroll
        for (int q = 0; q < 32; ++q) {
            const float w = gW3[q * 3 + lane];
            oA = fmaf(h2L[0][q], w, oA);
            oB = fmaf(h2L[1][q], w, oB);
        }
        nsA = fmaxf(oA, 0.0f) + statesrc[g0 * 3 + lane];
        nsB = fmaxf(oB, 0.0f) + statesrc[(g0 + 1) * 3 + lane];
        statedst[g0 * 3 + lane] = nsA;
        statedst[(g0 + 1) * 3 + lane] = nsB;
    }
    if (do_phi) {
        const float sa0 = __shfl(nsA, 0), sa1 = __shfl(nsA, 1), sa2 = __shfl(nsA, 2);
        const float sb0 = __shfl(nsB, 0), sb1 = __shfl(nsB, 1), sb2 = __shfl(nsB, 2);
        phi2_stage(fW1n, fb1n, fW2n, fb2n, fW3n, fb3n,
                   sa0, sa1, sa2, sb0, sb1, sb2, lane, H1, H2,
                   phidst + (size_t)g0 * 128, phidst + (size_t)(g0 + 1) * 128);
    }
}

extern "C" void kernel_launch(void* const* d_in, const int* in_sizes, int n_in,
                              void* d_out, int out_size, void* d_ws, size_t ws_size,
                              hipStream_t stream) {
    const float* x   = (const float*)d_in[0];
    // d_in[1..6] = hW1..hb3 : provably unused (delta MLP receives exact zeros)
    const float* fW1 = (const float*)d_in[7];
    const float* fb1 = (const float*)d_in[8];
    const float* fW2 = (const float*)d_in[9];
    const float* fb2 = (const float*)d_in[10];
    const float* fW3 = (const float*)d_in[11];
    const float* fb3 = (const float*)d_in[12];
    const float* gW1 = (const float*)d_in[13];
    const float* gb1 = (const float*)d_in[14];
    const float* gW2 = (const float*)d_in[15];
    const float* gb2 = (const float*)d_in[16];
    const float* gW3 = (const float*)d_in[17];
    const float* gb3 = (const float*)d_in[18];

    char* ws = (char*)d_ws;
    unsigned short* lists = (unsigned short*)(ws + 0);
    int* cnt              = (int*)(ws + 1179648);
    float* phiA           = (float*)(ws + 1185792);
    float* phiB           = (float*)(ws + 1972224);
    float* stateA         = (float*)(ws + 2758656);
    float* stateB         = (float*)(ws + 2777088);
    float* outp           = (float*)d_out;

    // K0: adj + phi0 -> phiA
    adj_phi0_kernel<<<768, 64, 0, stream>>>(x, fW1, fb1, fW2, fb2, fW3, fb3,
                                            cnt, lists, phiA);
    // K1: agg0+g0 (x -> stateA) + phi1 -> phiB
    step_kernel<<<768, 64, 0, stream>>>(phiA, phiB, cnt, lists, x, stateA,
                                        gW1, gb1, gW2, gb2, gW3, gb3,
                                        fW1 + 384, fb1 + 64, fW2 + 8192, fb2 + 128,
                                        fW3 + 16384, fb3 + 128, 1);
    // K2: agg1+g1 (stateA -> stateB) + phi2 -> phiA
    step_kernel<<<768, 64, 0, stream>>>(phiB, phiA, cnt, lists, stateA, stateB,
                                        gW1 + 8192, gb1 + 64, gW2 + 2048, gb2 + 32,
                                        gW3 + 96, gb3 + 3,
                                        fW1 + 768, fb1 + 128, fW2 + 16384, fb2 + 256,
                                        fW3 + 32768, fb3 + 256, 1);
    // K3: agg2+g2 (stateB -> out)
    step_kernel<<<768, 64, 0, stream>>>(phiA, phiB, cnt, lists, stateB, outp,
                                        gW1 + 16384, gb1 + 128, gW2 + 4096, gb2 + 64,
                                        gW3 + 192, gb3 + 6,
                                        fW1, fb1, fW2, fb2, fW3, fb3, 0);
}